// Round 6
// baseline (309.493 us; speedup 1.0000x reference)
//
#include <hip/hip_runtime.h>
#include <hip/hip_cooperative_groups.h>
#include <math.h>

namespace cg = cooperative_groups;

#define DD 1024   // total dim
#define NN 128    // nodes
#define BB 8      // batch
#define KNBR 8    // neighbors
#define NH 8      // heads
#define LL 128    // latent

typedef __attribute__((ext_vector_type(8))) short short8v;
typedef __attribute__((ext_vector_type(4))) float f32x4;

#define GLDS(gptr, lptr)                                                      \
  __builtin_amdgcn_global_load_lds(                                           \
      (const __attribute__((address_space(1))) void*)(gptr),                  \
      (__attribute__((address_space(3))) void*)(lptr), 16, 0, 0)

__device__ __forceinline__ unsigned short f2bf(float x) {
  unsigned u = __float_as_uint(x);
  unsigned r = u + 0x7fff + ((u >> 16) & 1);   // round-to-nearest-even
  return (unsigned short)(r >> 16);
}
__device__ __forceinline__ float bf2f(unsigned short u) {
  return __uint_as_float((unsigned)u << 16);
}

// ---------------------------------------------------------------------------
// Single cooperative kernel, 768 blocks x 256 threads, 3 blocks/CU (48KB LDS).
// Phase 1: convert E -> bf16 (512 blocks' threads), transpose+convert W
//          (one 64x64 tile per block).            [proven R4 bodies]
// Phase 2: 3-matrix MFMA GEMM, 64x64 tiles, 3-buffer counted-vmcnt pipeline.
// Phase 3: gather + per-head softmax epilogue (jobs bid, bid+768).
// ---------------------------------------------------------------------------
__global__ __launch_bounds__(256, 3)
void colight_fused(const float* __restrict__ E, const float* __restrict__ adj,
                   const float* __restrict__ Wl, const float* __restrict__ bl,
                   const float* __restrict__ Wa, const float* __restrict__ ba,
                   const float* __restrict__ Wh, const float* __restrict__ bh,
                   unsigned short* __restrict__ Eb, unsigned short* __restrict__ Wt,
                   float* __restrict__ Yl, unsigned short* __restrict__ Yab,
                   unsigned short* __restrict__ Yhb, float* __restrict__ out) {
  __shared__ __align__(16) char smem[49152];

  const int bid = blockIdx.x;
  const int t = threadIdx.x;
  cg::grid_group grid = cg::this_grid();

  // ========================== Phase 1: prep ================================
  {
    // E convert: chunk c (8 elems) for c < 131072 (first 512 blocks' threads)
    const int c = bid * 256 + t;
    if (c < 131072) {
      const int i = c * 8;
      float4 a = *(const float4*)&E[i];
      float4 d = *(const float4*)&E[i + 4];
      union { unsigned short u[8]; uint4 v; } o;
      o.u[0] = f2bf(a.x); o.u[1] = f2bf(a.y); o.u[2] = f2bf(a.z); o.u[3] = f2bf(a.w);
      o.u[4] = f2bf(d.x); o.u[5] = f2bf(d.y); o.u[6] = f2bf(d.z); o.u[7] = f2bf(d.w);
      *(uint4*)&Eb[i] = o.v;
    }

    // W transpose tile: one 64x64 tile per block
    const int z = bid >> 8;            // mat 0..2
    const int tidx = bid & 255;
    const int bxp = tidx & 15, byp = tidx >> 4;
    const float* W = (z == 0) ? Wl : (z == 1) ? Wa : Wh;
    unsigned short* wout = Wt + (size_t)z * DD * DD;

    unsigned short (*tile)[65] = (unsigned short(*)[65])smem;
    const int tx = t & 15, ty = t >> 4;
    const int r0 = byp * 64, c0 = bxp * 64;

    #pragma unroll
    for (int i = 0; i < 4; ++i) {
      const int r = ty + i * 16;
      float4 v = *(const float4*)&W[(size_t)(r0 + r) * DD + c0 + tx * 4];
      tile[r][tx * 4 + 0] = f2bf(v.x);
      tile[r][tx * 4 + 1] = f2bf(v.y);
      tile[r][tx * 4 + 2] = f2bf(v.z);
      tile[r][tx * 4 + 3] = f2bf(v.w);
    }
    __syncthreads();
    #pragma unroll
    for (int i = 0; i < 4; ++i) {
      const int rr = ty + i * 16;   // output row = W column c0+rr
      ushort4 o;
      o.x = tile[tx * 4 + 0][rr];
      o.y = tile[tx * 4 + 1][rr];
      o.z = tile[tx * 4 + 2][rr];
      o.w = tile[tx * 4 + 3][rr];
      *(ushort4*)&wout[(size_t)(c0 + rr) * DD + r0 + tx * 4] = o;
    }
  }

  __threadfence();
  grid.sync();

  // ========================== Phase 2: GEMM ================================
  {
    const int job = (bid & 7) * 96 + (bid >> 3);   // bijective XCD swizzle
    const int mat = job >> 8;
    const int rem = job & 255;
    const int bx = rem >> 4;           // col panel 0..15
    const int by = rem & 15;           // row panel 0..15

    const unsigned short* Bg = Wt + (size_t)mat * DD * DD;
    const float* bias = (mat == 0) ? bl : (mat == 1) ? ba : bh;

    unsigned short* Asm = (unsigned short*)smem;          // 3 x 4096 elems
    unsigned short* Bsm = (unsigned short*)smem + 12288;  // 3 x 4096 elems

    const int lane = t & 63;
    const int w = t >> 6;            // wave 0..3
    const int wr = w >> 1, wc = w & 1;
    const int brow = by * 64, bcol = bx * 64;

    // staging: thread t -> tile row (t>>3) [+32 for 2nd issue], chunk (t&7).
    // swizzle: LDS row r, linear chunk q holds global chunk q ^ (r&7).
    const int srow = t >> 3;                      // 0..31
    const int sk = (((t & 7) ^ (srow & 7)) * 8);  // source k-offset (elems)
    const unsigned short* gA = Eb + (size_t)(brow + srow) * DD + sk;
    const unsigned short* gB = Bg + (size_t)(bcol + srow) * DD + sk;
    const int ldsoff = w * 512;   // elems; wave-uniform base (+ lane*16B by HW)

    const int lrow = lane & 15, lg = lane >> 4;

    int aidx[2][2], bidx[2][2];
    #pragma unroll
    for (int kk = 0; kk < 2; ++kk)
      #pragma unroll
      for (int m = 0; m < 2; ++m) {
        const int ra = wr * 32 + m * 16 + lrow;
        aidx[kk][m] = ra * 64 + (((kk * 4 + lg) ^ (ra & 7)) * 8);
        const int rb = wc * 32 + m * 16 + lrow;
        bidx[kk][m] = rb * 64 + (((kk * 4 + lg) ^ (rb & 7)) * 8);
      }

    // preload bias and force completion so loop vmcnt counting stays exact
    float bv0 = bias[bcol + wc * 32 + lrow];
    float bv1 = bias[bcol + wc * 32 + 16 + lrow];
    asm volatile("" : "+v"(bv0), "+v"(bv1));

    f32x4 acc[2][2] = {};

#define STAGE(q, kt) do {                                                     \
    const int k0_ = (kt) * 64;                                                \
    GLDS(gA + k0_,           Asm + (q) * 4096 + ldsoff);                      \
    GLDS(gA + k0_ + 32 * DD, Asm + (q) * 4096 + 2048 + ldsoff);               \
    GLDS(gB + k0_,           Bsm + (q) * 4096 + ldsoff);                      \
    GLDS(gB + k0_ + 32 * DD, Bsm + (q) * 4096 + 2048 + ldsoff);               \
  } while (0)

    STAGE(0, 0);   // 4 vm ops in flight
    STAGE(1, 1);   // 8 in flight

    #pragma unroll
    for (int kt = 0; kt < 16; ++kt) {
      const int p = kt % 3;
      if (kt != 15) asm volatile("s_waitcnt vmcnt(4)" ::: "memory");
      else          asm volatile("s_waitcnt vmcnt(0)" ::: "memory");
      __builtin_amdgcn_s_barrier();   // buf p landed; reads of buf (p+2)%3 done
      if (kt + 2 < 16) STAGE((kt + 2) % 3, kt + 2);

      short8v a[2][2], b[2][2];
      #pragma unroll
      for (int kk = 0; kk < 2; ++kk)
        #pragma unroll
        for (int m = 0; m < 2; ++m) {
          a[kk][m] = *(const short8v*)&Asm[p * 4096 + aidx[kk][m]];
          b[kk][m] = *(const short8v*)&Bsm[p * 4096 + bidx[kk][m]];
        }

      #pragma unroll
      for (int kk = 0; kk < 2; ++kk)
        #pragma unroll
        for (int m = 0; m < 2; ++m)
          #pragma unroll
          for (int n = 0; n < 2; ++n)
            acc[m][n] = __builtin_amdgcn_mfma_f32_16x16x32_bf16(
                a[kk][m], b[kk][n], acc[m][n], 0, 0, 0);
    }
#undef STAGE

    // C-write: bias + relu (C/D: col = lane&15, row = (lane>>4)*4 + j)
    #pragma unroll
    for (int m = 0; m < 2; ++m) {
      #pragma unroll
      for (int n = 0; n < 2; ++n) {
        const int col = bcol + wc * 32 + n * 16 + lrow;
        const int r0  = brow + wr * 32 + m * 16 + lg * 4;
        const float bv = n ? bv1 : bv0;
        if (mat == 0) {
          #pragma unroll
          for (int j = 0; j < 4; ++j)
            Yl[(size_t)(r0 + j) * DD + col] = fmaxf(acc[m][n][j] + bv, 0.f);
        } else {
          unsigned short* Yo = (mat == 1) ? Yab : Yhb;
          #pragma unroll
          for (int j = 0; j < 4; ++j)
            Yo[(size_t)(r0 + j) * DD + col] = f2bf(fmaxf(acc[m][n][j] + bv, 0.f));
        }
      }
    }
  }

  __threadfence();
  grid.sync();

  // ========================= Phase 3: epilogue =============================
  {
    struct Epi {
      int   idxs[KNBR];
      float sA[DD];
      float sH[DD];
      float sL[DD];
      float sPart[NH][LL];
    };
    Epi* sh = (Epi*)smem;   // 16416 B

    for (int job = bid; job < BB * NN; job += 768) {
      const int bi = (job & 7) * NN + (job >> 3);   // batch job&7 -> XCD job&7
      const int b  = bi >> 7;

      // one-hot scan: group k = t>>5 scans its 128-float row as float4
      const float* arow = adj + (size_t)bi * KNBR * NN;
      {
        const int k = t >> 5, j = t & 31;
        float4 v = *(const float4*)&arow[k * NN + j * 4];
        const int base = j * 4;
        if (v.x > 0.5f) sh->idxs[k] = base;
        if (v.y > 0.5f) sh->idxs[k] = base + 1;
        if (v.z > 0.5f) sh->idxs[k] = base + 2;
        if (v.w > 0.5f) sh->idxs[k] = base + 3;
      }
      __syncthreads();

      const int rbase = b * NN;
      int ridx[KNBR];
      #pragma unroll
      for (int k = 0; k < KNBR; ++k) ridx[k] = rbase + sh->idxs[k];

      // gather + sum 8 neighbor rows (bf16 short4 = 8B/lane, coalesced)
      const int d0 = t * 4;
      {
        float a0 = 0.f, a1 = 0.f, a2 = 0.f, a3 = 0.f;
        float h0 = 0.f, h1 = 0.f, h2 = 0.f, h3 = 0.f;
        #pragma unroll
        for (int k = 0; k < KNBR; ++k) {
          const size_t rr = (size_t)ridx[k] * DD + d0;
          ushort4 va = *(const ushort4*)&Yab[rr];
          ushort4 vh = *(const ushort4*)&Yhb[rr];
          a0 += bf2f(va.x); a1 += bf2f(va.y); a2 += bf2f(va.z); a3 += bf2f(va.w);
          h0 += bf2f(vh.x); h1 += bf2f(vh.y); h2 += bf2f(vh.z); h3 += bf2f(vh.w);
        }
        float4 sa = {a0, a1, a2, a3};
        float4 shv = {h0, h1, h2, h3};
        *(float4*)&sh->sA[d0] = sa;
        *(float4*)&sh->sH[d0] = shv;
        *(float4*)&sh->sL[d0] = *(const float4*)&Yl[(size_t)bi * DD + d0];
      }
      __syncthreads();

      // per-head softmax over L=128: head h = t>>5, lane j = t&31
      const int h = t >> 5, j = t & 31;
      float z[4];
      float mx = -1e30f;
      #pragma unroll
      for (int q = 0; q < 4; ++q) {
        const int l = j + q * 32;
        z[q] = sh->sL[l * NH + h] * sh->sA[l * NH + h];
        mx = fmaxf(mx, z[q]);
      }
      #pragma unroll
      for (int m = 1; m <= 16; m <<= 1)
        mx = fmaxf(mx, __shfl_xor(mx, m, 32));

      float se = 0.f;
      #pragma unroll
      for (int q = 0; q < 4; ++q) {
        z[q] = expf(z[q] - mx);
        se += z[q];
      }
      #pragma unroll
      for (int m = 1; m <= 16; m <<= 1)
        se += __shfl_xor(se, m, 32);
      const float inv = 1.f / se;

      #pragma unroll
      for (int q = 0; q < 4; ++q) {
        const int l = j + q * 32;
        sh->sPart[h][l] = z[q] * inv * sh->sH[l * NH + h] * 0.125f;
      }
      __syncthreads();

      if (t < LL) {
        float o = 0.f;
        #pragma unroll
        for (int hh = 0; hh < NH; ++hh) o += sh->sPart[hh][t];
        out[(size_t)bi * LL + t] = o;
      }
      __syncthreads();   // job's sPart reads done before next job reuses smem
    }
  }
}

// ---------------------------------------------------------------------------
extern "C" void kernel_launch(void* const* d_in, const int* in_sizes, int n_in,
                              void* d_out, int out_size, void* d_ws, size_t ws_size,
                              hipStream_t stream) {
  const float* E   = (const float*)d_in[0];
  const float* adj = (const float*)d_in[1];
  const float* Wl  = (const float*)d_in[2];
  const float* bl  = (const float*)d_in[3];
  const float* Wa  = (const float*)d_in[4];
  const float* ba  = (const float*)d_in[5];
  const float* Wh  = (const float*)d_in[6];
  const float* bh  = (const float*)d_in[7];
  float* out = (float*)d_out;

  char* ws = (char*)d_ws;
  float*          Yl  = (float*)ws;                                // 4 MB
  unsigned short* Yab = (unsigned short*)(ws + 4  * 1024 * 1024);  // 2 MB
  unsigned short* Yhb = (unsigned short*)(ws + 6  * 1024 * 1024);  // 2 MB
  unsigned short* Eb  = (unsigned short*)(ws + 8  * 1024 * 1024);  // 2 MB
  unsigned short* Wt  = (unsigned short*)(ws + 10 * 1024 * 1024);  // 6 MB

  void* args[] = {(void*)&E,  (void*)&adj, (void*)&Wl, (void*)&bl,
                  (void*)&Wa, (void*)&ba,  (void*)&Wh, (void*)&bh,
                  (void*)&Eb, (void*)&Wt,  (void*)&Yl, (void*)&Yab,
                  (void*)&Yhb, (void*)&out};
  hipLaunchCooperativeKernel((const void*)colight_fused, dim3(768), dim3(256),
                             args, 0, stream);
}

// Round 7
// 187.070 us; speedup vs baseline: 1.6544x; 1.6544x over previous
//
#include <hip/hip_runtime.h>
#include <math.h>

#define DD 1024   // total dim
#define NN 128    // nodes
#define BB 8      // batch
#define KNBR 8    // neighbors
#define NH 8      // heads
#define LL 128    // latent
#define NBLK 768  // grid size (3 blocks/CU x 256 CU)

typedef __attribute__((ext_vector_type(8))) short short8v;
typedef __attribute__((ext_vector_type(4))) float f32x4;

#define GLDS(gptr, lptr)                                                      \
  __builtin_amdgcn_global_load_lds(                                           \
      (const __attribute__((address_space(1))) void*)(gptr),                  \
      (__attribute__((address_space(3))) void*)(lptr), 16, 0, 0)

__device__ __forceinline__ unsigned short f2bf(float x) {
  unsigned u = __float_as_uint(x);
  unsigned r = u + 0x7fff + ((u >> 16) & 1);   // round-to-nearest-even
  return (unsigned short)(r >> 16);
}
__device__ __forceinline__ float bf2f(unsigned short u) {
  return __uint_as_float((unsigned)u << 16);
}

// hand-rolled grid barrier: lead-thread atomic count + acquire spin.
// Counters zeroed per launch by hipMemsetAsync. Device(agent)-scope
// release/acquire gives cross-XCD visibility (same semantics the implicit
// kernel-boundary flush provided in the 3-kernel version).
__device__ __forceinline__ void global_barrier(unsigned* cnt) {
  __syncthreads();
  if (threadIdx.x == 0) {
    __threadfence();   // release all my block's prior writes
    __hip_atomic_fetch_add(cnt, 1u, __ATOMIC_ACQ_REL, __HIP_MEMORY_SCOPE_AGENT);
    unsigned v;
    do {
      __builtin_amdgcn_s_sleep(2);
      v = __hip_atomic_load(cnt, __ATOMIC_ACQUIRE, __HIP_MEMORY_SCOPE_AGENT);
    } while (v < (unsigned)NBLK);
  }
  __syncthreads();
}

// ---------------------------------------------------------------------------
// Single kernel, 768 blocks x 256 threads, 3 blocks/CU (48KB LDS).
// Phase 1: convert E -> bf16; transpose+convert W (one 64x64 tile per block).
// Phase 2: 3-matrix MFMA GEMM, 64x64 tiles, 3-buffer counted-vmcnt pipeline.
// Phase 3: gather + per-head softmax epilogue.
// All phase bodies byte-identical to the validated R5 kernel; only the
// inter-phase sync changed (grid.sync -> hand barrier).
// ---------------------------------------------------------------------------
__global__ __launch_bounds__(256, 3)
void colight_fused(const float* __restrict__ E, const float* __restrict__ adj,
                   const float* __restrict__ Wl, const float* __restrict__ bl,
                   const float* __restrict__ Wa, const float* __restrict__ ba,
                   const float* __restrict__ Wh, const float* __restrict__ bh,
                   unsigned short* __restrict__ Eb, unsigned short* __restrict__ Wt,
                   float* __restrict__ Yl, unsigned short* __restrict__ Yab,
                   unsigned short* __restrict__ Yhb, float* __restrict__ out,
                   unsigned* __restrict__ barrier_cnt) {
  __shared__ __align__(16) char smem[49152];

  const int bid = blockIdx.x;
  const int t = threadIdx.x;

  // ========================== Phase 1: prep ================================
  {
    // E convert: chunk c (8 elems) for c < 131072 (first 512 blocks' threads)
    const int c = bid * 256 + t;
    if (c < 131072) {
      const int i = c * 8;
      float4 a = *(const float4*)&E[i];
      float4 d = *(const float4*)&E[i + 4];
      union { unsigned short u[8]; uint4 v; } o;
      o.u[0] = f2bf(a.x); o.u[1] = f2bf(a.y); o.u[2] = f2bf(a.z); o.u[3] = f2bf(a.w);
      o.u[4] = f2bf(d.x); o.u[5] = f2bf(d.y); o.u[6] = f2bf(d.z); o.u[7] = f2bf(d.w);
      *(uint4*)&Eb[i] = o.v;
    }

    // W transpose tile: one 64x64 tile per block
    const int z = bid >> 8;            // mat 0..2
    const int tidx = bid & 255;
    const int bxp = tidx & 15, byp = tidx >> 4;
    const float* W = (z == 0) ? Wl : (z == 1) ? Wa : Wh;
    unsigned short* wout = Wt + (size_t)z * DD * DD;

    unsigned short (*tile)[65] = (unsigned short(*)[65])smem;
    const int tx = t & 15, ty = t >> 4;
    const int r0 = byp * 64, c0 = bxp * 64;

    #pragma unroll
    for (int i = 0; i < 4; ++i) {
      const int r = ty + i * 16;
      float4 v = *(const float4*)&W[(size_t)(r0 + r) * DD + c0 + tx * 4];
      tile[r][tx * 4 + 0] = f2bf(v.x);
      tile[r][tx * 4 + 1] = f2bf(v.y);
      tile[r][tx * 4 + 2] = f2bf(v.z);
      tile[r][tx * 4 + 3] = f2bf(v.w);
    }
    __syncthreads();
    #pragma unroll
    for (int i = 0; i < 4; ++i) {
      const int rr = ty + i * 16;   // output row = W column c0+rr
      ushort4 o;
      o.x = tile[tx * 4 + 0][rr];
      o.y = tile[tx * 4 + 1][rr];
      o.z = tile[tx * 4 + 2][rr];
      o.w = tile[tx * 4 + 3][rr];
      *(ushort4*)&wout[(size_t)(c0 + rr) * DD + r0 + tx * 4] = o;
    }
  }

  global_barrier(&barrier_cnt[0]);

  // ========================== Phase 2: GEMM ================================
  {
    // drain t0's barrier atomics so loop vmcnt counting stays exact
    asm volatile("s_waitcnt vmcnt(0) lgkmcnt(0)" ::: "memory");

    const int job = (bid & 7) * 96 + (bid >> 3);   // bijective XCD swizzle
    const int mat = job >> 8;
    const int rem = job & 255;
    const int bx = rem >> 4;           // col panel 0..15
    const int by = rem & 15;           // row panel 0..15

    const unsigned short* Bg = Wt + (size_t)mat * DD * DD;
    const float* bias = (mat == 0) ? bl : (mat == 1) ? ba : bh;

    unsigned short* Asm = (unsigned short*)smem;          // 3 x 4096 elems
    unsigned short* Bsm = (unsigned short*)smem + 12288;  // 3 x 4096 elems

    const int lane = t & 63;
    const int w = t >> 6;            // wave 0..3
    const int wr = w >> 1, wc = w & 1;
    const int brow = by * 64, bcol = bx * 64;

    // staging: thread t -> tile row (t>>3) [+32 for 2nd issue], chunk (t&7).
    // swizzle: LDS row r, linear chunk q holds global chunk q ^ (r&7).
    const int srow = t >> 3;                      // 0..31
    const int sk = (((t & 7) ^ (srow & 7)) * 8);  // source k-offset (elems)
    const unsigned short* gA = Eb + (size_t)(brow + srow) * DD + sk;
    const unsigned short* gB = Bg + (size_t)(bcol + srow) * DD + sk;
    const int ldsoff = w * 512;   // elems; wave-uniform base (+ lane*16B by HW)

    const int lrow = lane & 15, lg = lane >> 4;

    int aidx[2][2], bidx[2][2];
    #pragma unroll
    for (int kk = 0; kk < 2; ++kk)
      #pragma unroll
      for (int m = 0; m < 2; ++m) {
        const int ra = wr * 32 + m * 16 + lrow;
        aidx[kk][m] = ra * 64 + (((kk * 4 + lg) ^ (ra & 7)) * 8);
        const int rb = wc * 32 + m * 16 + lrow;
        bidx[kk][m] = rb * 64 + (((kk * 4 + lg) ^ (rb & 7)) * 8);
      }

    // preload bias and force completion so loop vmcnt counting stays exact
    float bv0 = bias[bcol + wc * 32 + lrow];
    float bv1 = bias[bcol + wc * 32 + 16 + lrow];
    asm volatile("" : "+v"(bv0), "+v"(bv1));

    f32x4 acc[2][2] = {};

#define STAGE(q, kt) do {                                                     \
    const int k0_ = (kt) * 64;                                                \
    GLDS(gA + k0_,           Asm + (q) * 4096 + ldsoff);                      \
    GLDS(gA + k0_ + 32 * DD, Asm + (q) * 4096 + 2048 + ldsoff);               \
    GLDS(gB + k0_,           Bsm + (q) * 4096 + ldsoff);                      \
    GLDS(gB + k0_ + 32 * DD, Bsm + (q) * 4096 + 2048 + ldsoff);               \
  } while (0)

    STAGE(0, 0);   // 4 vm ops in flight
    STAGE(1, 1);   // 8 in flight

    #pragma unroll
    for (int kt = 0; kt < 16; ++kt) {
      const int p = kt % 3;
      if (kt != 15) asm volatile("s_waitcnt vmcnt(4)" ::: "memory");
      else          asm volatile("s_waitcnt vmcnt(0)" ::: "memory");
      __builtin_amdgcn_s_barrier();   // buf p landed; reads of buf (p+2)%3 done
      if (kt + 2 < 16) STAGE((kt + 2) % 3, kt + 2);

      short8v a[2][2], b[2][2];
      #pragma unroll
      for (int kk = 0; kk < 2; ++kk)
        #pragma unroll
        for (int m = 0; m < 2; ++m) {
          a[kk][m] = *(const short8v*)&Asm[p * 4096 + aidx[kk][m]];
          b[kk][m] = *(const short8v*)&Bsm[p * 4096 + bidx[kk][m]];
        }

      #pragma unroll
      for (int kk = 0; kk < 2; ++kk)
        #pragma unroll
        for (int m = 0; m < 2; ++m)
          #pragma unroll
          for (int n = 0; n < 2; ++n)
            acc[m][n] = __builtin_amdgcn_mfma_f32_16x16x32_bf16(
                a[kk][m], b[kk][n], acc[m][n], 0, 0, 0);
    }
#undef STAGE

    // C-write: bias + relu (C/D: col = lane&15, row = (lane>>4)*4 + j)
    #pragma unroll
    for (int m = 0; m < 2; ++m) {
      #pragma unroll
      for (int n = 0; n < 2; ++n) {
        const int col = bcol + wc * 32 + n * 16 + lrow;
        const int r0  = brow + wr * 32 + m * 16 + lg * 4;
        const float bv = n ? bv1 : bv0;
        if (mat == 0) {
          #pragma unroll
          for (int j = 0; j < 4; ++j)
            Yl[(size_t)(r0 + j) * DD + col] = fmaxf(acc[m][n][j] + bv, 0.f);
        } else {
          unsigned short* Yo = (mat == 1) ? Yab : Yhb;
          #pragma unroll
          for (int j = 0; j < 4; ++j)
            Yo[(size_t)(r0 + j) * DD + col] = f2bf(fmaxf(acc[m][n][j] + bv, 0.f));
        }
      }
    }
  }

  global_barrier(&barrier_cnt[1]);

  // ========================= Phase 3: epilogue =============================
  {
    struct Epi {
      int   idxs[KNBR];
      float sA[DD];
      float sH[DD];
      float sL[DD];
      float sPart[NH][LL];
    };
    Epi* sh = (Epi*)smem;   // 16416 B

    for (int job = bid; job < BB * NN; job += NBLK) {
      const int bi = (job & 7) * NN + (job >> 3);   // batch job&7 -> XCD job&7
      const int b  = bi >> 7;

      // one-hot scan: group k = t>>5 scans its 128-float row as float4
      const float* arow = adj + (size_t)bi * KNBR * NN;
      {
        const int k = t >> 5, j = t & 31;
        float4 v = *(const float4*)&arow[k * NN + j * 4];
        const int base = j * 4;
        if (v.x > 0.5f) sh->idxs[k] = base;
        if (v.y > 0.5f) sh->idxs[k] = base + 1;
        if (v.z > 0.5f) sh->idxs[k] = base + 2;
        if (v.w > 0.5f) sh->idxs[k] = base + 3;
      }
      __syncthreads();

      const int rbase = b * NN;
      int ridx[KNBR];
      #pragma unroll
      for (int k = 0; k < KNBR; ++k) ridx[k] = rbase + sh->idxs[k];

      // gather + sum 8 neighbor rows (bf16 short4 = 8B/lane, coalesced)
      const int d0 = t * 4;
      {
        float a0 = 0.f, a1 = 0.f, a2 = 0.f, a3 = 0.f;
        float h0 = 0.f, h1 = 0.f, h2 = 0.f, h3 = 0.f;
        #pragma unroll
        for (int k = 0; k < KNBR; ++k) {
          const size_t rr = (size_t)ridx[k] * DD + d0;
          ushort4 va = *(const ushort4*)&Yab[rr];
          ushort4 vh = *(const ushort4*)&Yhb[rr];
          a0 += bf2f(va.x); a1 += bf2f(va.y); a2 += bf2f(va.z); a3 += bf2f(va.w);
          h0 += bf2f(vh.x); h1 += bf2f(vh.y); h2 += bf2f(vh.z); h3 += bf2f(vh.w);
        }
        float4 sa = {a0, a1, a2, a3};
        float4 shv = {h0, h1, h2, h3};
        *(float4*)&sh->sA[d0] = sa;
        *(float4*)&sh->sH[d0] = shv;
        *(float4*)&sh->sL[d0] = *(const float4*)&Yl[(size_t)bi * DD + d0];
      }
      __syncthreads();

      // per-head softmax over L=128: head h = t>>5, lane j = t&31
      const int h = t >> 5, j = t & 31;
      float z[4];
      float mx = -1e30f;
      #pragma unroll
      for (int q = 0; q < 4; ++q) {
        const int l = j + q * 32;
        z[q] = sh->sL[l * NH + h] * sh->sA[l * NH + h];
        mx = fmaxf(mx, z[q]);
      }
      #pragma unroll
      for (int m = 1; m <= 16; m <<= 1)
        mx = fmaxf(mx, __shfl_xor(mx, m, 32));

      float se = 0.f;
      #pragma unroll
      for (int q = 0; q < 4; ++q) {
        z[q] = expf(z[q] - mx);
        se += z[q];
      }
      #pragma unroll
      for (int m = 1; m <= 16; m <<= 1)
        se += __shfl_xor(se, m, 32);
      const float inv = 1.f / se;

      #pragma unroll
      for (int q = 0; q < 4; ++q) {
        const int l = j + q * 32;
        sh->sPart[h][l] = z[q] * inv * sh->sH[l * NH + h] * 0.125f;
      }
      __syncthreads();

      if (t < LL) {
        float o = 0.f;
        #pragma unroll
        for (int hh = 0; hh < NH; ++hh) o += sh->sPart[hh][t];
        out[(size_t)bi * LL + t] = o;
      }
      __syncthreads();   // job's sPart reads done before next job reuses smem
    }
  }
}

// ---------------------------------------------------------------------------
extern "C" void kernel_launch(void* const* d_in, const int* in_sizes, int n_in,
                              void* d_out, int out_size, void* d_ws, size_t ws_size,
                              hipStream_t stream) {
  const float* E   = (const float*)d_in[0];
  const float* adj = (const float*)d_in[1];
  const float* Wl  = (const float*)d_in[2];
  const float* bl  = (const float*)d_in[3];
  const float* Wa  = (const float*)d_in[4];
  const float* ba  = (const float*)d_in[5];
  const float* Wh  = (const float*)d_in[6];
  const float* bh  = (const float*)d_in[7];
  float* out = (float*)d_out;

  char* ws = (char*)d_ws;
  float*          Yl  = (float*)ws;                                // 4 MB
  unsigned short* Yab = (unsigned short*)(ws + 4  * 1024 * 1024);  // 2 MB
  unsigned short* Yhb = (unsigned short*)(ws + 6  * 1024 * 1024);  // 2 MB
  unsigned short* Eb  = (unsigned short*)(ws + 8  * 1024 * 1024);  // 2 MB
  unsigned short* Wt  = (unsigned short*)(ws + 10 * 1024 * 1024);  // 6 MB
  unsigned*       cnt = (unsigned*)(ws + 16 * 1024 * 1024);        // 8 B

  hipMemsetAsync(cnt, 0, 2 * sizeof(unsigned), stream);

  colight_fused<<<dim3(NBLK), dim3(256), 0, stream>>>(
      E, adj, Wl, bl, Wa, ba, Wh, bh, Eb, Wt, Yl, Yab, Yhb, out, cnt);
}

// Round 8
// 148.420 us; speedup vs baseline: 2.0852x; 1.2604x over previous
//
#include <hip/hip_runtime.h>
#include <math.h>

#define DD 1024   // total dim
#define NN 128    // nodes
#define BB 8      // batch
#define KNBR 8    // neighbors
#define NH 8      // heads
#define LL 128    // latent
#define NBLK 768  // grid size (3 blocks/CU x 256 CU)

typedef __attribute__((ext_vector_type(8))) short short8v;
typedef __attribute__((ext_vector_type(4))) float f32x4;

#define GLDS(gptr, lptr)                                                      \
  __builtin_amdgcn_global_load_lds(                                           \
      (const __attribute__((address_space(1))) void*)(gptr),                  \
      (__attribute__((address_space(3))) void*)(lptr), 16, 0, 0)

__device__ __forceinline__ unsigned short f2bf(float x) {
  unsigned u = __float_as_uint(x);
  unsigned r = u + 0x7fff + ((u >> 16) & 1);   // round-to-nearest-even
  return (unsigned short)(r >> 16);
}
__device__ __forceinline__ float bf2f(unsigned short u) {
  return __uint_as_float((unsigned)u << 16);
}

// Grid barrier, invalidate-free spin:
//  - release __threadfence once, RELAXED fetch_add to 1-of-8 padded counters
//  - spin on RELAXED loads (no per-iteration buffer_inv, reads reach the
//    coherence point since they are agent-scope atomics)
//  - single acquire __threadfence after exit.
// Counters zeroed per launch by hipMemsetAsync.
__device__ __forceinline__ void global_barrier(unsigned* cnts) {
  __syncthreads();
  if (threadIdx.x == 0) {
    __threadfence();   // release: write back my block's prior writes
    __hip_atomic_fetch_add(&cnts[(blockIdx.x & 7) * 16], 1u,
                           __ATOMIC_RELAXED, __HIP_MEMORY_SCOPE_AGENT);
    unsigned sum;
    do {
      __builtin_amdgcn_s_sleep(4);
      sum = 0;
      #pragma unroll
      for (int i = 0; i < 8; ++i)
        sum += __hip_atomic_load(&cnts[i * 16], __ATOMIC_RELAXED,
                                 __HIP_MEMORY_SCOPE_AGENT);
    } while (sum < (unsigned)NBLK);
    __threadfence();   // acquire: invalidate stale caches before remote reads
  }
  __syncthreads();
}

// ---------------------------------------------------------------------------
// Single kernel, 768 blocks x 256 threads, 3 blocks/CU (48KB LDS).
// Phase 1: convert E -> bf16; transpose+convert W (one 64x64 tile per block).
// Phase 2: 3-matrix MFMA GEMM, 64x64 tiles, 3-buffer counted-vmcnt pipeline.
// Phase 3: gather + per-head softmax epilogue.
// Phase bodies byte-identical to validated R5/R6; only barrier impl changed.
// ---------------------------------------------------------------------------
__global__ __launch_bounds__(256, 3)
void colight_fused(const float* __restrict__ E, const float* __restrict__ adj,
                   const float* __restrict__ Wl, const float* __restrict__ bl,
                   const float* __restrict__ Wa, const float* __restrict__ ba,
                   const float* __restrict__ Wh, const float* __restrict__ bh,
                   unsigned short* __restrict__ Eb, unsigned short* __restrict__ Wt,
                   float* __restrict__ Yl, unsigned short* __restrict__ Yab,
                   unsigned short* __restrict__ Yhb, float* __restrict__ out,
                   unsigned* __restrict__ barrier_cnt) {
  __shared__ __align__(16) char smem[49152];

  const int bid = blockIdx.x;
  const int t = threadIdx.x;

  // ========================== Phase 1: prep ================================
  {
    // E convert: chunk c (8 elems) for c < 131072 (first 512 blocks' threads)
    const int c = bid * 256 + t;
    if (c < 131072) {
      const int i = c * 8;
      float4 a = *(const float4*)&E[i];
      float4 d = *(const float4*)&E[i + 4];
      union { unsigned short u[8]; uint4 v; } o;
      o.u[0] = f2bf(a.x); o.u[1] = f2bf(a.y); o.u[2] = f2bf(a.z); o.u[3] = f2bf(a.w);
      o.u[4] = f2bf(d.x); o.u[5] = f2bf(d.y); o.u[6] = f2bf(d.z); o.u[7] = f2bf(d.w);
      *(uint4*)&Eb[i] = o.v;
    }

    // W transpose tile: one 64x64 tile per block
    const int z = bid >> 8;            // mat 0..2
    const int tidx = bid & 255;
    const int bxp = tidx & 15, byp = tidx >> 4;
    const float* W = (z == 0) ? Wl : (z == 1) ? Wa : Wh;
    unsigned short* wout = Wt + (size_t)z * DD * DD;

    unsigned short (*tile)[65] = (unsigned short(*)[65])smem;
    const int tx = t & 15, ty = t >> 4;
    const int r0 = byp * 64, c0 = bxp * 64;

    #pragma unroll
    for (int i = 0; i < 4; ++i) {
      const int r = ty + i * 16;
      float4 v = *(const float4*)&W[(size_t)(r0 + r) * DD + c0 + tx * 4];
      tile[r][tx * 4 + 0] = f2bf(v.x);
      tile[r][tx * 4 + 1] = f2bf(v.y);
      tile[r][tx * 4 + 2] = f2bf(v.z);
      tile[r][tx * 4 + 3] = f2bf(v.w);
    }
    __syncthreads();
    #pragma unroll
    for (int i = 0; i < 4; ++i) {
      const int rr = ty + i * 16;   // output row = W column c0+rr
      ushort4 o;
      o.x = tile[tx * 4 + 0][rr];
      o.y = tile[tx * 4 + 1][rr];
      o.z = tile[tx * 4 + 2][rr];
      o.w = tile[tx * 4 + 3][rr];
      *(ushort4*)&wout[(size_t)(c0 + rr) * DD + r0 + tx * 4] = o;
    }
  }

  global_barrier(&barrier_cnt[0]);

  // ========================== Phase 2: GEMM ================================
  {
    // drain t0's barrier/spin memory ops so loop vmcnt counting stays exact
    asm volatile("s_waitcnt vmcnt(0) lgkmcnt(0)" ::: "memory");

    const int job = (bid & 7) * 96 + (bid >> 3);   // bijective XCD swizzle
    const int mat = job >> 8;
    const int rem = job & 255;
    const int bx = rem >> 4;           // col panel 0..15
    const int by = rem & 15;           // row panel 0..15

    const unsigned short* Bg = Wt + (size_t)mat * DD * DD;
    const float* bias = (mat == 0) ? bl : (mat == 1) ? ba : bh;

    unsigned short* Asm = (unsigned short*)smem;          // 3 x 4096 elems
    unsigned short* Bsm = (unsigned short*)smem + 12288;  // 3 x 4096 elems

    const int lane = t & 63;
    const int w = t >> 6;            // wave 0..3
    const int wr = w >> 1, wc = w & 1;
    const int brow = by * 64, bcol = bx * 64;

    // staging: thread t -> tile row (t>>3) [+32 for 2nd issue], chunk (t&7).
    // swizzle: LDS row r, linear chunk q holds global chunk q ^ (r&7).
    const int srow = t >> 3;                      // 0..31
    const int sk = (((t & 7) ^ (srow & 7)) * 8);  // source k-offset (elems)
    const unsigned short* gA = Eb + (size_t)(brow + srow) * DD + sk;
    const unsigned short* gB = Bg + (size_t)(bcol + srow) * DD + sk;
    const int ldsoff = w * 512;   // elems; wave-uniform base (+ lane*16B by HW)

    const int lrow = lane & 15, lg = lane >> 4;

    int aidx[2][2], bidx[2][2];
    #pragma unroll
    for (int kk = 0; kk < 2; ++kk)
      #pragma unroll
      for (int m = 0; m < 2; ++m) {
        const int ra = wr * 32 + m * 16 + lrow;
        aidx[kk][m] = ra * 64 + (((kk * 4 + lg) ^ (ra & 7)) * 8);
        const int rb = wc * 32 + m * 16 + lrow;
        bidx[kk][m] = rb * 64 + (((kk * 4 + lg) ^ (rb & 7)) * 8);
      }

    // preload bias and force completion so loop vmcnt counting stays exact
    float bv0 = bias[bcol + wc * 32 + lrow];
    float bv1 = bias[bcol + wc * 32 + 16 + lrow];
    asm volatile("" : "+v"(bv0), "+v"(bv1));

    f32x4 acc[2][2] = {};

#define STAGE(q, kt) do {                                                     \
    const int k0_ = (kt) * 64;                                                \
    GLDS(gA + k0_,           Asm + (q) * 4096 + ldsoff);                      \
    GLDS(gA + k0_ + 32 * DD, Asm + (q) * 4096 + 2048 + ldsoff);               \
    GLDS(gB + k0_,           Bsm + (q) * 4096 + ldsoff);                      \
    GLDS(gB + k0_ + 32 * DD, Bsm + (q) * 4096 + 2048 + ldsoff);               \
  } while (0)

    STAGE(0, 0);   // 4 vm ops in flight
    STAGE(1, 1);   // 8 in flight

    #pragma unroll
    for (int kt = 0; kt < 16; ++kt) {
      const int p = kt % 3;
      if (kt != 15) asm volatile("s_waitcnt vmcnt(4)" ::: "memory");
      else          asm volatile("s_waitcnt vmcnt(0)" ::: "memory");
      __builtin_amdgcn_s_barrier();   // buf p landed; reads of buf (p+2)%3 done
      if (kt + 2 < 16) STAGE((kt + 2) % 3, kt + 2);

      short8v a[2][2], b[2][2];
      #pragma unroll
      for (int kk = 0; kk < 2; ++kk)
        #pragma unroll
        for (int m = 0; m < 2; ++m) {
          a[kk][m] = *(const short8v*)&Asm[p * 4096 + aidx[kk][m]];
          b[kk][m] = *(const short8v*)&Bsm[p * 4096 + bidx[kk][m]];
        }

      #pragma unroll
      for (int kk = 0; kk < 2; ++kk)
        #pragma unroll
        for (int m = 0; m < 2; ++m)
          #pragma unroll
          for (int n = 0; n < 2; ++n)
            acc[m][n] = __builtin_amdgcn_mfma_f32_16x16x32_bf16(
                a[kk][m], b[kk][n], acc[m][n], 0, 0, 0);
    }
#undef STAGE

    // C-write: bias + relu (C/D: col = lane&15, row = (lane>>4)*4 + j)
    #pragma unroll
    for (int m = 0; m < 2; ++m) {
      #pragma unroll
      for (int n = 0; n < 2; ++n) {
        const int col = bcol + wc * 32 + n * 16 + lrow;
        const int r0  = brow + wr * 32 + m * 16 + lg * 4;
        const float bv = n ? bv1 : bv0;
        if (mat == 0) {
          #pragma unroll
          for (int j = 0; j < 4; ++j)
            Yl[(size_t)(r0 + j) * DD + col] = fmaxf(acc[m][n][j] + bv, 0.f);
        } else {
          unsigned short* Yo = (mat == 1) ? Yab : Yhb;
          #pragma unroll
          for (int j = 0; j < 4; ++j)
            Yo[(size_t)(r0 + j) * DD + col] = f2bf(fmaxf(acc[m][n][j] + bv, 0.f));
        }
      }
    }
  }

  global_barrier(&barrier_cnt[128]);

  // ========================= Phase 3: epilogue =============================
  {
    struct Epi {
      int   idxs[KNBR];
      float sA[DD];
      float sH[DD];
      float sL[DD];
      float sPart[NH][LL];
    };
    Epi* sh = (Epi*)smem;   // 16416 B

    for (int job = bid; job < BB * NN; job += NBLK) {
      const int bi = (job & 7) * NN + (job >> 3);   // batch job&7 -> XCD job&7
      const int b  = bi >> 7;

      // one-hot scan: group k = t>>5 scans its 128-float row as float4
      const float* arow = adj + (size_t)bi * KNBR * NN;
      {
        const int k = t >> 5, j = t & 31;
        float4 v = *(const float4*)&arow[k * NN + j * 4];
        const int base = j * 4;
        if (v.x > 0.5f) sh->idxs[k] = base;
        if (v.y > 0.5f) sh->idxs[k] = base + 1;
        if (v.z > 0.5f) sh->idxs[k] = base + 2;
        if (v.w > 0.5f) sh->idxs[k] = base + 3;
      }
      __syncthreads();

      const int rbase = b * NN;
      int ridx[KNBR];
      #pragma unroll
      for (int k = 0; k < KNBR; ++k) ridx[k] = rbase + sh->idxs[k];

      // gather + sum 8 neighbor rows (bf16 short4 = 8B/lane, coalesced)
      const int d0 = t * 4;
      {
        float a0 = 0.f, a1 = 0.f, a2 = 0.f, a3 = 0.f;
        float h0 = 0.f, h1 = 0.f, h2 = 0.f, h3 = 0.f;
        #pragma unroll
        for (int k = 0; k < KNBR; ++k) {
          const size_t rr = (size_t)ridx[k] * DD + d0;
          ushort4 va = *(const ushort4*)&Yab[rr];
          ushort4 vh = *(const ushort4*)&Yhb[rr];
          a0 += bf2f(va.x); a1 += bf2f(va.y); a2 += bf2f(va.z); a3 += bf2f(va.w);
          h0 += bf2f(vh.x); h1 += bf2f(vh.y); h2 += bf2f(vh.z); h3 += bf2f(vh.w);
        }
        float4 sa = {a0, a1, a2, a3};
        float4 shv = {h0, h1, h2, h3};
        *(float4*)&sh->sA[d0] = sa;
        *(float4*)&sh->sH[d0] = shv;
        *(float4*)&sh->sL[d0] = *(const float4*)&Yl[(size_t)bi * DD + d0];
      }
      __syncthreads();

      // per-head softmax over L=128: head h = t>>5, lane j = t&31
      const int h = t >> 5, j = t & 31;
      float z[4];
      float mx = -1e30f;
      #pragma unroll
      for (int q = 0; q < 4; ++q) {
        const int l = j + q * 32;
        z[q] = sh->sL[l * NH + h] * sh->sA[l * NH + h];
        mx = fmaxf(mx, z[q]);
      }
      #pragma unroll
      for (int m = 1; m <= 16; m <<= 1)
        mx = fmaxf(mx, __shfl_xor(mx, m, 32));

      float se = 0.f;
      #pragma unroll
      for (int q = 0; q < 4; ++q) {
        z[q] = expf(z[q] - mx);
        se += z[q];
      }
      #pragma unroll
      for (int m = 1; m <= 16; m <<= 1)
        se += __shfl_xor(se, m, 32);
      const float inv = 1.f / se;

      #pragma unroll
      for (int q = 0; q < 4; ++q) {
        const int l = j + q * 32;
        sh->sPart[h][l] = z[q] * inv * sh->sH[l * NH + h] * 0.125f;
      }
      __syncthreads();

      if (t < LL) {
        float o = 0.f;
        #pragma unroll
        for (int hh = 0; hh < NH; ++hh) o += sh->sPart[hh][t];
        out[(size_t)bi * LL + t] = o;
      }
      __syncthreads();   // job's sPart reads done before next job reuses smem
    }
  }
}

// ---------------------------------------------------------------------------
extern "C" void kernel_launch(void* const* d_in, const int* in_sizes, int n_in,
                              void* d_out, int out_size, void* d_ws, size_t ws_size,
                              hipStream_t stream) {
  const float* E   = (const float*)d_in[0];
  const float* adj = (const float*)d_in[1];
  const float* Wl  = (const float*)d_in[2];
  const float* bl  = (const float*)d_in[3];
  const float* Wa  = (const float*)d_in[4];
  const float* ba  = (const float*)d_in[5];
  const float* Wh  = (const float*)d_in[6];
  const float* bh  = (const float*)d_in[7];
  float* out = (float*)d_out;

  char* ws = (char*)d_ws;
  float*          Yl  = (float*)ws;                                // 4 MB
  unsigned short* Yab = (unsigned short*)(ws + 4  * 1024 * 1024);  // 2 MB
  unsigned short* Yhb = (unsigned short*)(ws + 6  * 1024 * 1024);  // 2 MB
  unsigned short* Eb  = (unsigned short*)(ws + 8  * 1024 * 1024);  // 2 MB
  unsigned short* Wt  = (unsigned short*)(ws + 10 * 1024 * 1024);  // 6 MB
  unsigned*       cnt = (unsigned*)(ws + 16 * 1024 * 1024);        // 1 KB

  // 2 barriers x 8 padded counters (64B apart) = 256 unsigned
  hipMemsetAsync(cnt, 0, 256 * sizeof(unsigned), stream);

  colight_fused<<<dim3(NBLK), dim3(256), 0, stream>>>(
      E, adj, Wl, bl, Wa, ba, Wh, bh, Eb, Wt, Yl, Yab, Yhb, out, cnt);
}

// Round 9
// 27.911 us; speedup vs baseline: 11.0887x; 5.3177x over previous
//
#include <hip/hip_runtime.h>
#include <math.h>

#define DD 1024   // total dim
#define NN 128    // nodes
#define BB 8      // batch
#define KNBR 8    // neighbors
#define NH 8      // heads
#define LL 128    // latent

typedef __attribute__((ext_vector_type(8))) short short8v;
typedef __attribute__((ext_vector_type(4))) float f32x4;

#define GLDS(gptr, lptr)                                                      \
  __builtin_amdgcn_global_load_lds(                                           \
      (const __attribute__((address_space(1))) void*)(gptr),                  \
      (__attribute__((address_space(3))) void*)(lptr), 16, 0, 0)

__device__ __forceinline__ unsigned short f2bf(float x) {
  unsigned u = __float_as_uint(x);
  unsigned r = u + 0x7fff + ((u >> 16) & 1);   // round-to-nearest-even
  return (unsigned short)(r >> 16);
}
__device__ __forceinline__ float bf2f(unsigned short u) {
  return __uint_as_float((unsigned)u << 16);
}

// ---------------------------------------------------------------------------
// Prep: z<3 -> convert+transpose W[z] (64x64 LDS tiles); z==3 -> convert E.
// grid (16,16,4), 256 threads.   [proven since R2]
// ---------------------------------------------------------------------------
__global__ __launch_bounds__(256)
void prep(const float* __restrict__ E,
          const float* __restrict__ Wl, const float* __restrict__ Wa,
          const float* __restrict__ Wh,
          unsigned short* __restrict__ Eb, unsigned short* __restrict__ Wt) {
  const int z = blockIdx.z;
  const int t = threadIdx.x;

  if (z == 3) {   // E convert: 256 blocks x 256 threads x 16 elems
    const int bid = blockIdx.y * 16 + blockIdx.x;
    const int i0 = bid * 4096 + t * 16;
    #pragma unroll
    for (int q = 0; q < 2; ++q) {
      const int i = i0 + q * 8;
      float4 a = *(const float4*)&E[i];
      float4 c = *(const float4*)&E[i + 4];
      union { unsigned short u[8]; uint4 v; } o;
      o.u[0] = f2bf(a.x); o.u[1] = f2bf(a.y); o.u[2] = f2bf(a.z); o.u[3] = f2bf(a.w);
      o.u[4] = f2bf(c.x); o.u[5] = f2bf(c.y); o.u[6] = f2bf(c.z); o.u[7] = f2bf(c.w);
      *(uint4*)&Eb[i] = o.v;
    }
    return;
  }

  const float* W = (z == 0) ? Wl : (z == 1) ? Wa : Wh;
  unsigned short* out = Wt + (size_t)z * DD * DD;

  __shared__ unsigned short tile[64][65];
  const int tx = t & 15, ty = t >> 4;
  const int r0 = blockIdx.y * 64, c0 = blockIdx.x * 64;

  #pragma unroll
  for (int i = 0; i < 4; ++i) {
    const int r = ty + i * 16;
    float4 v = *(const float4*)&W[(size_t)(r0 + r) * DD + c0 + tx * 4];
    tile[r][tx * 4 + 0] = f2bf(v.x);
    tile[r][tx * 4 + 1] = f2bf(v.y);
    tile[r][tx * 4 + 2] = f2bf(v.z);
    tile[r][tx * 4 + 3] = f2bf(v.w);
  }
  __syncthreads();
  #pragma unroll
  for (int i = 0; i < 4; ++i) {
    const int rr = ty + i * 16;   // output row = W column c0+rr
    ushort4 o;
    o.x = tile[tx * 4 + 0][rr];
    o.y = tile[tx * 4 + 1][rr];
    o.z = tile[tx * 4 + 2][rr];
    o.w = tile[tx * 4 + 3][rr];
    *(ushort4*)&out[(size_t)(c0 + rr) * DD + r0 + tx * 4] = o;
  }
}

// ---------------------------------------------------------------------------
// MFMA GEMM: Y[mat] = relu(Eb @ W[mat] + b[mat]), bf16 in / bf16 out (all 3).
// 64x64 tile, BK=64, 256 threads = 4 waves, wave tile 32x32.
// 3-buffer LDS, 2-tile-deep prefetch, counted vmcnt(4) + raw s_barrier.
// XOR-swizzled tiles. 1D grid 768, bijective XCD swizzle.
// setprio(1) around the MFMA cluster (3 independent blocks/CU arbitrate).
// ---------------------------------------------------------------------------
__global__ __launch_bounds__(256)
void gemm3_mfma(const unsigned short* __restrict__ Eb,
                const unsigned short* __restrict__ Wt,
                const float* __restrict__ bl, const float* __restrict__ ba,
                const float* __restrict__ bh,
                unsigned short* __restrict__ Ylb,
                unsigned short* __restrict__ Yab,
                unsigned short* __restrict__ Yhb) {
  const int orig = blockIdx.x;
  const int job = (orig & 7) * 96 + (orig >> 3);
  const int mat = job >> 8;          // /256
  const int rem = job & 255;
  const int bx = rem >> 4;           // col panel 0..15
  const int by = rem & 15;           // row panel 0..15

  const unsigned short* Bg = Wt + (size_t)mat * DD * DD;
  const float* bias = (mat == 0) ? bl : (mat == 1) ? ba : bh;

  __shared__ unsigned short As[3][64 * 64];
  __shared__ unsigned short Bs[3][64 * 64];

  const int t = threadIdx.x;
  const int lane = t & 63;
  const int w = t >> 6;            // wave 0..3
  const int wr = w >> 1, wc = w & 1;
  const int brow = by * 64, bcol = bx * 64;

  // staging: thread t -> tile row (t>>3) [+32 for 2nd issue], chunk (t&7).
  // swizzle: LDS row r, linear chunk q holds global chunk q ^ (r&7).
  const int srow = t >> 3;                      // 0..31
  const int sk = (((t & 7) ^ (srow & 7)) * 8);  // source k-offset (elems)
  const unsigned short* gA = Eb + (size_t)(brow + srow) * DD + sk;
  const unsigned short* gB = Bg + (size_t)(bcol + srow) * DD + sk;
  const int ldsoff = w * 512;   // elems; wave-uniform base (+ lane*16B by HW)

  const int lrow = lane & 15, lg = lane >> 4;

  // swizzled fragment indices: row r, logical chunk (kk*4+lg) -> chunk^(r&7)
  int aidx[2][2], bidx[2][2];
  #pragma unroll
  for (int kk = 0; kk < 2; ++kk)
    #pragma unroll
    for (int m = 0; m < 2; ++m) {
      const int ra = wr * 32 + m * 16 + lrow;
      aidx[kk][m] = ra * 64 + (((kk * 4 + lg) ^ (ra & 7)) * 8);
      const int rb = wc * 32 + m * 16 + lrow;
      bidx[kk][m] = rb * 64 + (((kk * 4 + lg) ^ (rb & 7)) * 8);
    }

  // preload bias and force completion so loop vmcnt counting stays exact
  float bv0 = bias[bcol + wc * 32 + lrow];
  float bv1 = bias[bcol + wc * 32 + 16 + lrow];
  asm volatile("" : "+v"(bv0), "+v"(bv1));   // materialize (drains their loads)

  f32x4 acc[2][2] = {};

#define STAGE(q, kt) do {                                                     \
    const int k0_ = (kt) * 64;                                                \
    GLDS(gA + k0_,           &As[q][ldsoff]);                                 \
    GLDS(gA + k0_ + 32 * DD, &As[q][2048 + ldsoff]);                          \
    GLDS(gB + k0_,           &Bs[q][ldsoff]);                                 \
    GLDS(gB + k0_ + 32 * DD, &Bs[q][2048 + ldsoff]);                          \
  } while (0)

  STAGE(0, 0);   // 4 vm ops in flight
  STAGE(1, 1);   // 8 in flight

  #pragma unroll
  for (int kt = 0; kt < 16; ++kt) {
    const int p = kt % 3;
    // wait for tile kt's 4 loads (oldest); tile kt+1's 4 stay in flight
    if (kt != 15) asm volatile("s_waitcnt vmcnt(4)" ::: "memory");
    else          asm volatile("s_waitcnt vmcnt(0)" ::: "memory");
    __builtin_amdgcn_s_barrier();   // all waves' slices of buf p landed;
                                    // also: all reads of buf (p+2)%3 done
    if (kt + 2 < 16) STAGE((kt + 2) % 3, kt + 2);   // overwrite tile kt-1's buf

    short8v a[2][2], b[2][2];
    #pragma unroll
    for (int kk = 0; kk < 2; ++kk)
      #pragma unroll
      for (int m = 0; m < 2; ++m) {
        a[kk][m] = *(const short8v*)&As[p][aidx[kk][m]];
        b[kk][m] = *(const short8v*)&Bs[p][bidx[kk][m]];
      }

    __builtin_amdgcn_s_setprio(1);
    #pragma unroll
    for (int kk = 0; kk < 2; ++kk)
      #pragma unroll
      for (int m = 0; m < 2; ++m)
        #pragma unroll
        for (int n = 0; n < 2; ++n)
          acc[m][n] = __builtin_amdgcn_mfma_f32_16x16x32_bf16(
              a[kk][m], b[kk][n], acc[m][n], 0, 0, 0);
    __builtin_amdgcn_s_setprio(0);
  }
#undef STAGE

  // epilogue: bias + relu, bf16 store (C/D: col = lane&15, row = (lane>>4)*4+j)
  unsigned short* Yo = (mat == 0) ? Ylb : (mat == 1) ? Yab : Yhb;
  #pragma unroll
  for (int m = 0; m < 2; ++m) {
    #pragma unroll
    for (int n = 0; n < 2; ++n) {
      const int col = bcol + wc * 32 + n * 16 + lrow;
      const int r0  = brow + wr * 32 + m * 16 + lg * 4;
      const float bv = n ? bv1 : bv0;
      #pragma unroll
      for (int j = 0; j < 4; ++j)
        Yo[(size_t)(r0 + j) * DD + col] = f2bf(fmaxf(acc[m][n][j] + bv, 0.f));
    }
  }
}

// ---------------------------------------------------------------------------
// Epilogue: per (b,i) node -- gather neighbor rows of Ya/Yh (bf16, coalesced),
// head-major LDS staging (softmax reads 2-way bank = free, vs 8-way before),
// per-head softmax over L=128, head-mean output.
// XCD-swizzled: batch b -> XCD b (batch slabs L2-resident).
// ---------------------------------------------------------------------------
__global__ __launch_bounds__(256)
void colight_epilogue(const float* __restrict__ adj,
                      const unsigned short* __restrict__ Ylb,
                      const unsigned short* __restrict__ Yab,
                      const unsigned short* __restrict__ Yhb,
                      float* __restrict__ out) {
  const int bid = blockIdx.x;
  const int bi = (bid & 7) * NN + (bid >> 3);   // batch = bid&7 -> XCD bid&7
  const int b  = bi >> 7;

  __shared__ int   idxs[KNBR];
  __shared__ float sA[NH][LL];
  __shared__ float sH[NH][LL];
  __shared__ float sL[NH][LL];
  __shared__ float sPart[NH][LL];

  const int t = threadIdx.x;

  // one-hot scan: group k = t>>5 scans its 128-float row as float4
  const float* arow = adj + (size_t)bi * KNBR * NN;
  {
    const int k = t >> 5, j = t & 31;
    float4 v = *(const float4*)&arow[k * NN + j * 4];
    const int base = j * 4;
    if (v.x > 0.5f) idxs[k] = base;
    if (v.y > 0.5f) idxs[k] = base + 1;
    if (v.z > 0.5f) idxs[k] = base + 2;
    if (v.w > 0.5f) idxs[k] = base + 3;
  }
  __syncthreads();

  const int rbase = b * NN;
  int ridx[KNBR];
  #pragma unroll
  for (int k = 0; k < KNBR; ++k) ridx[k] = rbase + idxs[k];

  // gather + sum 8 neighbor rows; store head-major: d = l*8+h -> s[h][l].
  // thread t covers d0..d0+3: same l = t>>1, heads h0..h0+3 (h0 = (t&1)*4).
  const int d0 = t * 4;
  const int gl = t >> 1;            // latent index
  const int h0 = (t & 1) * 4;       // head group base
  {
    float a0 = 0.f, a1 = 0.f, a2 = 0.f, a3 = 0.f;
    float g0 = 0.f, g1 = 0.f, g2 = 0.f, g3 = 0.f;
    #pragma unroll
    for (int k = 0; k < KNBR; ++k) {
      const size_t rr = (size_t)ridx[k] * DD + d0;
      ushort4 va = *(const ushort4*)&Yab[rr];
      ushort4 vh = *(const ushort4*)&Yhb[rr];
      a0 += bf2f(va.x); a1 += bf2f(va.y); a2 += bf2f(va.z); a3 += bf2f(va.w);
      g0 += bf2f(vh.x); g1 += bf2f(vh.y); g2 += bf2f(vh.z); g3 += bf2f(vh.w);
    }
    ushort4 vl = *(const ushort4*)&Ylb[(size_t)bi * DD + d0];
    sA[h0 + 0][gl] = a0; sA[h0 + 1][gl] = a1;
    sA[h0 + 2][gl] = a2; sA[h0 + 3][gl] = a3;
    sH[h0 + 0][gl] = g0; sH[h0 + 1][gl] = g1;
    sH[h0 + 2][gl] = g2; sH[h0 + 3][gl] = g3;
    sL[h0 + 0][gl] = bf2f(vl.x); sL[h0 + 1][gl] = bf2f(vl.y);
    sL[h0 + 2][gl] = bf2f(vl.z); sL[h0 + 3][gl] = bf2f(vl.w);
  }
  __syncthreads();

  // per-head softmax over L=128: head h = t>>5, lane j = t&31, 4 elems/lane
  const int h = t >> 5, j = t & 31;
  float z[4];
  float mx = -1e30f;
  #pragma unroll
  for (int q = 0; q < 4; ++q) {
    const int l = j + q * 32;
    z[q] = sL[h][l] * sA[h][l];
    mx = fmaxf(mx, z[q]);
  }
  #pragma unroll
  for (int m = 1; m <= 16; m <<= 1)
    mx = fmaxf(mx, __shfl_xor(mx, m, 32));

  float se = 0.f;
  #pragma unroll
  for (int q = 0; q < 4; ++q) {
    z[q] = __expf(z[q] - mx);
    se += z[q];
  }
  #pragma unroll
  for (int m = 1; m <= 16; m <<= 1)
    se += __shfl_xor(se, m, 32);
  const float inv = 1.f / se;

  #pragma unroll
  for (int q = 0; q < 4; ++q) {
    const int l = j + q * 32;
    sPart[h][l] = z[q] * inv * sH[h][l] * 0.125f;  // mean over 8 heads
  }
  __syncthreads();

  if (t < LL) {
    float o = 0.f;
    #pragma unroll
    for (int hh = 0; hh < NH; ++hh) o += sPart[hh][t];
    out[(size_t)bi * LL + t] = o;
  }
}

// ---------------------------------------------------------------------------
extern "C" void kernel_launch(void* const* d_in, const int* in_sizes, int n_in,
                              void* d_out, int out_size, void* d_ws, size_t ws_size,
                              hipStream_t stream) {
  const float* E   = (const float*)d_in[0];
  const float* adj = (const float*)d_in[1];
  const float* Wl  = (const float*)d_in[2];
  const float* bl  = (const float*)d_in[3];
  const float* Wa  = (const float*)d_in[4];
  const float* ba  = (const float*)d_in[5];
  const float* Wh  = (const float*)d_in[6];
  const float* bh  = (const float*)d_in[7];
  float* out = (float*)d_out;

  char* ws = (char*)d_ws;
  unsigned short* Ylb = (unsigned short*)ws;                       // 2 MB
  unsigned short* Yab = (unsigned short*)(ws + 2 * 1024 * 1024);   // 2 MB
  unsigned short* Yhb = (unsigned short*)(ws + 4 * 1024 * 1024);   // 2 MB
  unsigned short* Eb  = (unsigned short*)(ws + 6 * 1024 * 1024);   // 2 MB
  unsigned short* Wt  = (unsigned short*)(ws + 8 * 1024 * 1024);   // 6 MB

  prep<<<dim3(16, 16, 4), dim3(256), 0, stream>>>(E, Wl, Wa, Wh, Eb, Wt);
  gemm3_mfma<<<dim3(768), dim3(256), 0, stream>>>(Eb, Wt, bl, ba, bh,
                                                  Ylb, Yab, Yhb);
  colight_epilogue<<<dim3(BB * NN), dim3(256), 0, stream>>>(adj, Ylb, Yab, Yhb, out);
}